// Round 4
// baseline (6124.355 us; speedup 1.0000x reference)
//
#include <hip/hip_runtime.h>

// Problem constants (from reference)
#define NPTS   8192   // N
#define NPT    2048   // NPOINT
#define NS     32     // NSAMPLE
#define CIN    64
#define BATCH  4
// threshold: f32 nearest to 0.64 (numpy/jax weak-type the python float 0.8**2 to f32)
#define R2     0.64f

// ---------------- prep: transpose weights into ws ----------------
__global__ __launch_bounds__(256) void prep_kernel(const float* __restrict__ w1,
                                                   const float* __restrict__ w2,
                                                   float* __restrict__ w1t,
                                                   float* __restrict__ w2t) {
  int i = blockIdx.x * 256 + threadIdx.x;
  if (i < 128 * 67) {
    int o = i / 67, c = i % 67;
    w1t[c * 128 + o] = w1[i];
  }
  if (i < 256 * 128) {
    int o = i >> 7, c = i & 127;
    w2t[c * 256 + o] = w2[i];
  }
}

// ---------------- Morton sort (separate kernel, u32 keys) ----------------
__device__ inline uint32_t part1by2(uint32_t x) {
  x &= 1023u;
  x = (x | (x << 16)) & 0x030000FFu;
  x = (x | (x << 8))  & 0x0300F00Fu;
  x = (x | (x << 4))  & 0x030C30C3u;
  x = (x | (x << 2))  & 0x09249249u;
  return x;
}

__device__ inline uint32_t morton3(float x, float y, float z) {
  int qx = (int)((x + 16.f) * 32.f);
  int qy = (int)((y + 16.f) * 32.f);
  int qz = (int)((z + 16.f) * 32.f);
  qx = qx < 0 ? 0 : (qx > 1023 ? 1023 : qx);
  qy = qy < 0 ? 0 : (qy > 1023 ? 1023 : qy);
  qz = qz < 0 ? 0 : (qz > 1023 ? 1023 : qz);
  return part1by2((uint32_t)qx) | (part1by2((uint32_t)qy) << 1) | (part1by2((uint32_t)qz) << 2);
}

// key = (morton top 19 bits << 13) | idx  -> unique keys, spatial order,
// idx recoverable from low 13 bits. Sort order only affects clustering
// quality, never correctness (min-updates are exact & order-independent).
__global__ __launch_bounds__(1024) void sort_kernel(const float* __restrict__ xyz,
                                                    float4* __restrict__ sorted) {
  const int b = blockIdx.x;
  const int tid = threadIdx.x;
  const float* X = xyz + (size_t)b * NPTS * 3;
  __shared__ uint32_t S[NPTS];  // 32 KB

  for (int k = 0; k < 8; ++k) {
    int p = tid + (k << 10);
    uint32_t m = morton3(X[p * 3 + 0], X[p * 3 + 1], X[p * 3 + 2]);
    S[p] = ((m >> 11) << 13) | (uint32_t)p;
  }
  __syncthreads();
  for (unsigned k = 2; k <= NPTS; k <<= 1) {
    for (unsigned j = k >> 1; j > 0; j >>= 1) {
      for (int i = tid; i < NPTS; i += 1024) {
        int l = i ^ (int)j;
        if (l > i) {
          uint32_t a = S[i], c = S[l];
          bool sw = ((i & k) == 0) ? (a > c) : (a < c);
          if (sw) { S[i] = c; S[l] = a; }
        }
      }
      __syncthreads();
    }
  }
  for (int k = 0; k < 8; ++k) {
    int pos = tid + (k << 10);
    int o = (int)(S[pos] & 8191u);
    float4 v;
    v.x = X[o * 3 + 0]; v.y = X[o * 3 + 1]; v.z = X[o * 3 + 2];
    v.w = __int_as_float(o);
    sorted[(size_t)b * NPTS + pos] = v;
  }
}

// ---------------- FPS v4: 4 waves, 32 pts/thread, 4x8 clusters ----------------
// Bit-exactness: min-updates use exact-rounded ((dx²+dy²)+dz²); a cluster is
// skipped only when conservative bbox lower bound (scaled 0.9999, dwarfing
// ~6e-7 relative rounding) >= cluster's current max dmin -> skipped updates
// provably change nothing. Argmax key (bits(dist)<<13)|(8191-idx) ties to
// smallest original index (numpy argmax).

#define DPP_ROR_STEP(kvar, ctrl)                                               \
  {                                                                            \
    int _lo = (int)(uint32_t)(kvar);                                           \
    int _hi = (int)(uint32_t)((kvar) >> 32);                                   \
    int _olo = __builtin_amdgcn_update_dpp(0, _lo, (ctrl), 0xF, 0xF, false);   \
    int _ohi = __builtin_amdgcn_update_dpp(0, _hi, (ctrl), 0xF, 0xF, false);   \
    uint64_t _o = ((uint64_t)(uint32_t)_ohi << 32) | (uint32_t)_olo;           \
    if (_o > (kvar)) (kvar) = _o;                                              \
  }

#define ROW_MAX_U64(kvar)                                                      \
  DPP_ROR_STEP(kvar, 0x121)  /* row_ror:1 */                                   \
  DPP_ROR_STEP(kvar, 0x122)  /* row_ror:2 */                                   \
  DPP_ROR_STEP(kvar, 0x124)  /* row_ror:4 */                                   \
  DPP_ROR_STEP(kvar, 0x128)  /* row_ror:8 */

__global__ __launch_bounds__(256) void fps_kernel(const float* __restrict__ xyz,
                                                  const float4* __restrict__ sorted,
                                                  float* __restrict__ new_xyz) {
  const int b = blockIdx.x;
  const int tid = threadIdx.x;     // 0..255
  const int lane = tid & 63;
  const int wv = tid >> 6;         // 0..3
  const float* X = xyz + (size_t)b * NPTS * 3;
  const float4* SP = sorted + (size_t)b * NPTS;

  __shared__ __align__(16) uint64_t rec[2][4];

  float px[32], py[32], pz[32], dmin[32];
  int oid[32];
#pragma unroll
  for (int k = 0; k < 32; ++k) {
    float4 p = SP[tid * 32 + k];
    px[k] = p.x; py[k] = p.y; pz[k] = p.z;
    oid[k] = __float_as_int(p.w);
    dmin[k] = 1e10f;
  }

  float bxmin[4], bxmax[4], bymin[4], bymax[4], bzmin[4], bzmax[4];
  float cmaxv[4]; int cmaxi[4];
#pragma unroll
  for (int c = 0; c < 4; ++c) {
    int k0 = c * 8;
    float xmn = px[k0], xmx = px[k0], ymn = py[k0], ymx = py[k0], zmn = pz[k0], zmx = pz[k0];
#pragma unroll
    for (int k = 1; k < 8; ++k) {
      xmn = fminf(xmn, px[k0 + k]); xmx = fmaxf(xmx, px[k0 + k]);
      ymn = fminf(ymn, py[k0 + k]); ymx = fmaxf(ymx, py[k0 + k]);
      zmn = fminf(zmn, pz[k0 + k]); zmx = fmaxf(zmx, pz[k0 + k]);
    }
    bxmin[c] = xmn; bxmax[c] = xmx;
    bymin[c] = ymn; bymax[c] = ymx;
    bzmin[c] = zmn; bzmax[c] = zmx;
    cmaxv[c] = 1e10f;        // forces full update at t=1 (dlb <= ~4096 < 1e10)
    cmaxi[c] = oid[k0];
  }

  float cx = X[0], cy = X[1], cz = X[2];
  if (tid == 0) {
    new_xyz[(size_t)b * NPT * 3 + 0] = cx;
    new_xyz[(size_t)b * NPT * 3 + 1] = cy;
    new_xyz[(size_t)b * NPT * 3 + 2] = cz;
  }

  for (int t = 1; t < NPT; ++t) {
#pragma unroll
    for (int c = 0; c < 4; ++c) {
      float ex = fmaxf(fmaxf(bxmin[c] - cx, cx - bxmax[c]), 0.f);
      float ey = fmaxf(fmaxf(bymin[c] - cy, cy - bymax[c]), 0.f);
      float ez = fmaxf(fmaxf(bzmin[c] - cz, cz - bzmax[c]), 0.f);
      float dlb = (ex * ex + ey * ey + ez * ez) * 0.9999f;
      if (dlb < cmaxv[c]) {
        float mv = -1.0f; int mi = 1 << 30;
#pragma unroll
        for (int k = c * 8; k < c * 8 + 8; ++k) {
          float dx = px[k] - cx, dy = py[k] - cy, dz = pz[k] - cz;
          float d = __fadd_rn(__fadd_rn(__fmul_rn(dx, dx), __fmul_rn(dy, dy)), __fmul_rn(dz, dz));
          float dm = fminf(dmin[k], d);
          dmin[k] = dm;
          bool bet = (dm > mv) || (dm == mv && oid[k] < mi);
          mv = bet ? dm : mv;
          mi = bet ? oid[k] : mi;
        }
        cmaxv[c] = mv; cmaxi[c] = mi;
      }
    }
    // thread best = merge of 4 cluster bests (exact tie-break: min orig idx)
    float bestv = cmaxv[0]; int besti = cmaxi[0];
#pragma unroll
    for (int c = 1; c < 4; ++c) {
      bool bet = (cmaxv[c] > bestv) || (cmaxv[c] == bestv && cmaxi[c] < besti);
      bestv = bet ? cmaxv[c] : bestv;
      besti = bet ? cmaxi[c] : besti;
    }
    uint64_t key = ((uint64_t)__float_as_uint(bestv) << 13) | (uint32_t)(8191 - besti);

    ROW_MAX_U64(key)   // every lane now has its 16-row's max
    uint32_t lo = (uint32_t)key, hi = (uint32_t)(key >> 32);
    uint64_t r0 = ((uint64_t)(uint32_t)__builtin_amdgcn_readlane((int)hi, 0)  << 32) | (uint32_t)__builtin_amdgcn_readlane((int)lo, 0);
    uint64_t r1 = ((uint64_t)(uint32_t)__builtin_amdgcn_readlane((int)hi, 16) << 32) | (uint32_t)__builtin_amdgcn_readlane((int)lo, 16);
    uint64_t r2 = ((uint64_t)(uint32_t)__builtin_amdgcn_readlane((int)hi, 32) << 32) | (uint32_t)__builtin_amdgcn_readlane((int)lo, 32);
    uint64_t r3 = ((uint64_t)(uint32_t)__builtin_amdgcn_readlane((int)hi, 48) << 32) | (uint32_t)__builtin_amdgcn_readlane((int)lo, 48);
    uint64_t wkey = r0;
    if (r1 > wkey) wkey = r1;
    if (r2 > wkey) wkey = r2;
    if (r3 > wkey) wkey = r3;

    const int buf = t & 1;
    if (lane == 0) rec[buf][wv] = wkey;
    __syncthreads();

    uint64_t k0 = rec[buf][0], k1 = rec[buf][1], k2 = rec[buf][2], k3 = rec[buf][3];
    uint64_t wk = k0;
    if (k1 > wk) wk = k1;
    if (k2 > wk) wk = k2;
    if (k3 > wk) wk = k3;

    int sidx = 8191 - (int)(wk & 8191u);
    sidx = __builtin_amdgcn_readfirstlane(sidx);   // force SGPR -> scalar loads
    const float* P = X + 3 * (size_t)sidx;
    cx = P[0]; cy = P[1]; cz = P[2];

    if (tid == 0) {
      float* o = new_xyz + ((size_t)b * NPT + t) * 3;
      o[0] = cx; o[1] = cy; o[2] = cz;
    }
  }
}

// ---------------- ball query: one wave per (b,s) ----------------
__global__ __launch_bounds__(256) void ballquery_kernel(const float* __restrict__ xyz,
                                                        const float* __restrict__ new_xyz,
                                                        int* __restrict__ idx_out) {
  const int w = blockIdx.x * 4 + (threadIdx.x >> 6);   // (b*2048 + s)
  const int lane = threadIdx.x & 63;
  const int b = w >> 11;
  const float* X = xyz + (size_t)b * NPTS * 3;
  const float cx = new_xyz[w * 3 + 0];
  const float cy = new_xyz[w * 3 + 1];
  const float cz = new_xyz[w * 3 + 2];
  int* out = idx_out + (size_t)w * NS;

  int found = 0;
  int first = -1;
  for (int base = 0; base < NPTS; base += 64) {
    const int p = base + lane;
    float x = X[p * 3 + 0], y = X[p * 3 + 1], z = X[p * 3 + 2];
    float dx = x - cx, dy = y - cy, dz = z - cz;
    float d2 = __fadd_rn(__fadd_rn(__fmul_rn(dx, dx), __fmul_rn(dy, dy)), __fmul_rn(dz, dz));
    unsigned long long mask = __ballot(d2 < R2);
    if (mask != 0ull && first < 0) first = base + __ffsll((unsigned long long)mask) - 1;
    if (found < NS) {
      if ((mask >> lane) & 1ull) {
        int rank = found + __popcll(mask & ((1ull << lane) - 1ull));
        if (rank < NS) out[rank] = p;
      }
    }
    found += __popcll(mask);
    if (found >= NS) break;
  }
  if (found < NS) {
    int pad = (first < 0) ? 0 : first;
    if (lane >= found && lane < NS) out[lane] = pad;
  }
}

// ---------------- group + MLP(67->128->256) + maxpool: one block per (b,s) ----------------
__global__ __launch_bounds__(256) void group_mlp_kernel(const float* __restrict__ xyz,
                                                        const float* __restrict__ feat,
                                                        const float* __restrict__ new_xyz,
                                                        const int* __restrict__ idx,
                                                        const float* __restrict__ w1t,
                                                        const float* __restrict__ b1,
                                                        const float* __restrict__ w2t,
                                                        const float* __restrict__ b2,
                                                        float* __restrict__ pooled) {
  const int blk = blockIdx.x;       // b*2048 + s
  const int b = blk >> 11, s = blk & 2047;
  const int tid = threadIdx.x;

  __shared__ __align__(16) float G[67 * 32];    // (C+3) x ns
  __shared__ __align__(16) float H1[128 * 32];  // 128 x ns
  __shared__ int   lidx[NS];
  __shared__ float ctr[3];

  if (tid < NS) lidx[tid] = idx[(size_t)blk * NS + tid];
  if (tid < 3)  ctr[tid] = new_xyz[blk * 3 + tid];
  __syncthreads();

  const float* F = feat + (size_t)b * CIN * NPTS;
  const float* X = xyz + (size_t)b * NPTS * 3;

  for (int e = tid; e < 67 * 32; e += 256) {
    int c = e >> 5, j = e & 31;
    int p = lidx[j];
    float v;
    if (c < 3) v = X[p * 3 + c] - ctr[c];
    else       v = F[(size_t)(c - 3) * NPTS + p];
    G[e] = v;
  }
  __syncthreads();

  // H1 = relu(W1 @ G + b1): 128x32, each thread 4o x 4j
  {
    const int oi = tid >> 3, ji = tid & 7;
    const int o0 = oi * 4, j0 = ji * 4;
    float acc[4][4];
#pragma unroll
    for (int i = 0; i < 4; ++i)
#pragma unroll
      for (int jj = 0; jj < 4; ++jj) acc[i][jj] = 0.f;
#pragma unroll 4
    for (int c = 0; c < 67; ++c) {
      float4 g  = *(const float4*)&G[c * 32 + j0];
      float4 wf = *(const float4*)&w1t[c * 128 + o0];
      float ga[4] = {g.x, g.y, g.z, g.w};
      float wa[4] = {wf.x, wf.y, wf.z, wf.w};
#pragma unroll
      for (int i = 0; i < 4; ++i)
#pragma unroll
        for (int jj = 0; jj < 4; ++jj)
          acc[i][jj] = fmaf(wa[i], ga[jj], acc[i][jj]);
    }
    float4 bb = *(const float4*)&b1[o0];
    float ba[4] = {bb.x, bb.y, bb.z, bb.w};
#pragma unroll
    for (int i = 0; i < 4; ++i) {
      float4 h;
      h.x = fmaxf(acc[i][0] + ba[i], 0.f);
      h.y = fmaxf(acc[i][1] + ba[i], 0.f);
      h.z = fmaxf(acc[i][2] + ba[i], 0.f);
      h.w = fmaxf(acc[i][3] + ba[i], 0.f);
      *(float4*)&H1[(o0 + i) * 32 + j0] = h;
    }
  }
  __syncthreads();

  // H2 = relu(W2 @ H1 + b2): 256x32, each thread 8o x 4j, then maxpool over j
  {
    const int oi = tid >> 3, ji = tid & 7;
    const int o0 = oi * 8, j0 = ji * 4;
    float acc[8][4];
#pragma unroll
    for (int i = 0; i < 8; ++i)
#pragma unroll
      for (int jj = 0; jj < 4; ++jj) acc[i][jj] = 0.f;
#pragma unroll 2
    for (int c = 0; c < 128; ++c) {
      float4 h  = *(const float4*)&H1[c * 32 + j0];
      float4 wa4 = *(const float4*)&w2t[c * 256 + o0];
      float4 wb4 = *(const float4*)&w2t[c * 256 + o0 + 4];
      float ha[4] = {h.x, h.y, h.z, h.w};
      float wa[8] = {wa4.x, wa4.y, wa4.z, wa4.w, wb4.x, wb4.y, wb4.z, wb4.w};
#pragma unroll
      for (int i = 0; i < 8; ++i)
#pragma unroll
        for (int jj = 0; jj < 4; ++jj)
          acc[i][jj] = fmaf(wa[i], ha[jj], acc[i][jj]);
    }
    float4 b2a = *(const float4*)&b2[o0];
    float4 b2b = *(const float4*)&b2[o0 + 4];
    float bb[8] = {b2a.x, b2a.y, b2a.z, b2a.w, b2b.x, b2b.y, b2b.z, b2b.w};
    float m[8];
#pragma unroll
    for (int i = 0; i < 8; ++i) {
      float v0 = fmaxf(acc[i][0] + bb[i], 0.f);
      float v1 = fmaxf(acc[i][1] + bb[i], 0.f);
      float v2 = fmaxf(acc[i][2] + bb[i], 0.f);
      float v3 = fmaxf(acc[i][3] + bb[i], 0.f);
      m[i] = fmaxf(fmaxf(v0, v1), fmaxf(v2, v3));
    }
#pragma unroll
    for (int off = 1; off < 8; off <<= 1)
#pragma unroll
      for (int i = 0; i < 8; ++i) m[i] = fmaxf(m[i], __shfl_xor(m[i], off));
    if (ji == 0) {
#pragma unroll
      for (int i = 0; i < 8; ++i)
        pooled[((size_t)b * 256 + o0 + i) * (size_t)NPT + s] = m[i];
    }
  }
}

extern "C" void kernel_launch(void* const* d_in, const int* in_sizes, int n_in,
                              void* d_out, int out_size, void* d_ws, size_t ws_size,
                              hipStream_t stream) {
  (void)in_sizes; (void)n_in; (void)out_size; (void)ws_size;
  const float* xyz  = (const float*)d_in[0];   // (4,8192,3)
  const float* feat = (const float*)d_in[1];   // (4,64,8192)
  const float* w1   = (const float*)d_in[2];   // (128,67)
  const float* b1   = (const float*)d_in[3];   // (128)
  const float* w2   = (const float*)d_in[4];   // (256,128)
  const float* b2   = (const float*)d_in[5];   // (256)

  float* out     = (float*)d_out;
  float* new_xyz = out;                        // (4,2048,3)
  float* pooled  = out + (size_t)BATCH * NPT * 3;  // (4,256,2048)

  char* ws = (char*)d_ws;
  float*  w1t    = (float*)ws;                         // 34304 B
  float*  w2t    = (float*)(ws + 34304);               // 131072 B
  int*    idx    = (int*)(ws + 34304 + 131072);        // 1048576 B
  float4* sorted = (float4*)(ws + 34304 + 131072 + 1048576);  // 524288 B (16B-aligned)

  prep_kernel<<<128, 256, 0, stream>>>(w1, w2, w1t, w2t);
  sort_kernel<<<BATCH, 1024, 0, stream>>>(xyz, sorted);
  fps_kernel<<<BATCH, 256, 0, stream>>>(xyz, sorted, new_xyz);
  ballquery_kernel<<<(BATCH * NPT) / 4, 256, 0, stream>>>(xyz, new_xyz, idx);
  group_mlp_kernel<<<BATCH * NPT, 256, 0, stream>>>(xyz, feat, new_xyz, idx,
                                                    w1t, b1, w2t, b2, pooled);
}

// Round 5
// 3927.335 us; speedup vs baseline: 1.5594x; 1.5594x over previous
//
#include <hip/hip_runtime.h>

// Problem constants (from reference)
#define NPTS   8192   // N
#define NPT    2048   // NPOINT
#define NS     32     // NSAMPLE
#define CIN    64
#define BATCH  4
// threshold: f32 nearest to 0.64 (numpy/jax weak-type the python float 0.8**2 to f32)
#define R2     0.64f

// ---------------- prep: transpose weights into ws ----------------
__global__ __launch_bounds__(256) void prep_kernel(const float* __restrict__ w1,
                                                   const float* __restrict__ w2,
                                                   float* __restrict__ w1t,
                                                   float* __restrict__ w2t) {
  int i = blockIdx.x * 256 + threadIdx.x;
  if (i < 128 * 67) {
    int o = i / 67, c = i % 67;
    w1t[c * 128 + o] = w1[i];
  }
  if (i < 256 * 128) {
    int o = i >> 7, c = i & 127;
    w2t[c * 256 + o] = w2[i];
  }
}

// ---------------- Morton sort (u32 keys, in-LDS bitonic) ----------------
__device__ inline uint32_t part1by2(uint32_t x) {
  x &= 1023u;
  x = (x | (x << 16)) & 0x030000FFu;
  x = (x | (x << 8))  & 0x0300F00Fu;
  x = (x | (x << 4))  & 0x030C30C3u;
  x = (x | (x << 2))  & 0x09249249u;
  return x;
}

__device__ inline uint32_t morton3(float x, float y, float z) {
  int qx = (int)((x + 16.f) * 32.f);
  int qy = (int)((y + 16.f) * 32.f);
  int qz = (int)((z + 16.f) * 32.f);
  qx = qx < 0 ? 0 : (qx > 1023 ? 1023 : qx);
  qy = qy < 0 ? 0 : (qy > 1023 ? 1023 : qy);
  qz = qz < 0 ? 0 : (qz > 1023 ? 1023 : qz);
  return part1by2((uint32_t)qx) | (part1by2((uint32_t)qy) << 1) | (part1by2((uint32_t)qz) << 2);
}

// key = (morton top 19 bits << 13) | idx. Sort order only affects clustering
// quality, never correctness (min-updates are exact & order-independent).
__global__ __launch_bounds__(1024) void sort_kernel(const float* __restrict__ xyz,
                                                    float4* __restrict__ sorted) {
  const int b = blockIdx.x;
  const int tid = threadIdx.x;
  const float* X = xyz + (size_t)b * NPTS * 3;
  __shared__ uint32_t S[NPTS];  // 32 KB

  for (int k = 0; k < 8; ++k) {
    int p = tid + (k << 10);
    uint32_t m = morton3(X[p * 3 + 0], X[p * 3 + 1], X[p * 3 + 2]);
    S[p] = ((m >> 11) << 13) | (uint32_t)p;
  }
  __syncthreads();
  for (unsigned k = 2; k <= NPTS; k <<= 1) {
    for (unsigned j = k >> 1; j > 0; j >>= 1) {
      for (int i = tid; i < NPTS; i += 1024) {
        int l = i ^ (int)j;
        if (l > i) {
          uint32_t a = S[i], c = S[l];
          bool sw = ((i & k) == 0) ? (a > c) : (a < c);
          if (sw) { S[i] = c; S[l] = a; }
        }
      }
      __syncthreads();
    }
  }
  for (int k = 0; k < 8; ++k) {
    int pos = tid + (k << 10);
    int o = (int)(S[pos] & 8191u);
    float4 v;
    v.x = X[o * 3 + 0]; v.y = X[o * 3 + 1]; v.z = X[o * 3 + 2];
    v.w = __int_as_float(o);
    sorted[(size_t)b * NPTS + pos] = v;
  }
}

// ---------------- FPS v5: 512 thr, 16 pts/thread (2x8 clusters), slim reduce ----
// Register budget: 5*16 + bbox(12) + cmax(4) + temps ~= 115 VGPR < 256 cap
// (launch_bounds(512,2)) -> no spill (R4's 32 pts/thread spilled and died).
// Bit-exactness (verified absmax 0.0 in R2/R3 with same math):
//  * exact-rounded ((dx²+dy²)+dz²) min-updates, order-independent;
//  * cluster skipped only if 0.9999-scaled conservative bbox lower bound
//    (rel rounding ~2e-7) >= cluster max dmin -> skip provably a no-op;
//  * argmax ties -> smallest original index at every stage.

#define DPP_ROR_U32_MAX(v)                                                       \
  {                                                                              \
    uint32_t _t;                                                                 \
    _t = (uint32_t)__builtin_amdgcn_update_dpp(0, (int)(v), 0x121, 0xF, 0xF, false); if (_t > (v)) (v) = _t; \
    _t = (uint32_t)__builtin_amdgcn_update_dpp(0, (int)(v), 0x122, 0xF, 0xF, false); if (_t > (v)) (v) = _t; \
    _t = (uint32_t)__builtin_amdgcn_update_dpp(0, (int)(v), 0x124, 0xF, 0xF, false); if (_t > (v)) (v) = _t; \
    _t = (uint32_t)__builtin_amdgcn_update_dpp(0, (int)(v), 0x128, 0xF, 0xF, false); if (_t > (v)) (v) = _t; \
  }

#define DPP_ROR_U32_MIN(v)                                                       \
  {                                                                              \
    uint32_t _t;                                                                 \
    _t = (uint32_t)__builtin_amdgcn_update_dpp(-1, (int)(v), 0x121, 0xF, 0xF, false); if (_t < (v)) (v) = _t; \
    _t = (uint32_t)__builtin_amdgcn_update_dpp(-1, (int)(v), 0x122, 0xF, 0xF, false); if (_t < (v)) (v) = _t; \
    _t = (uint32_t)__builtin_amdgcn_update_dpp(-1, (int)(v), 0x124, 0xF, 0xF, false); if (_t < (v)) (v) = _t; \
    _t = (uint32_t)__builtin_amdgcn_update_dpp(-1, (int)(v), 0x128, 0xF, 0xF, false); if (_t < (v)) (v) = _t; \
  }

__global__ __launch_bounds__(512, 2) void fps_kernel(const float* __restrict__ xyz,
                                                     const float4* __restrict__ sorted,
                                                     float* __restrict__ new_xyz) {
  const int b = blockIdx.x;
  const int tid = threadIdx.x;     // 0..511
  const int lane = tid & 63;
  const int wv = tid >> 6;         // 0..7
  const float* X = xyz + (size_t)b * NPTS * 3;
  const float4* SP = sorted + (size_t)b * NPTS;

  __shared__ __align__(16) uint64_t rec[2][8];

  float px[16], py[16], pz[16], dmin[16];
  int oid[16];
#pragma unroll
  for (int k = 0; k < 16; ++k) {
    float4 p = SP[tid * 16 + k];
    px[k] = p.x; py[k] = p.y; pz[k] = p.z;
    oid[k] = __float_as_int(p.w);
    dmin[k] = 1e10f;
  }

  float bxmin[2], bxmax[2], bymin[2], bymax[2], bzmin[2], bzmax[2];
  float cmaxv[2]; int cmaxi[2];
#pragma unroll
  for (int c = 0; c < 2; ++c) {
    int k0 = c * 8;
    float xmn = px[k0], xmx = px[k0], ymn = py[k0], ymx = py[k0], zmn = pz[k0], zmx = pz[k0];
#pragma unroll
    for (int k = 1; k < 8; ++k) {
      xmn = fminf(xmn, px[k0 + k]); xmx = fmaxf(xmx, px[k0 + k]);
      ymn = fminf(ymn, py[k0 + k]); ymx = fmaxf(ymx, py[k0 + k]);
      zmn = fminf(zmn, pz[k0 + k]); zmx = fmaxf(zmx, pz[k0 + k]);
    }
    bxmin[c] = xmn; bxmax[c] = xmx;
    bymin[c] = ymn; bymax[c] = ymx;
    bzmin[c] = zmn; bzmax[c] = zmx;
    cmaxv[c] = 1e10f;        // forces full update at t=1
    cmaxi[c] = oid[k0];
  }

  float cx = X[0], cy = X[1], cz = X[2];
  if (tid == 0) {
    new_xyz[(size_t)b * NPT * 3 + 0] = cx;
    new_xyz[(size_t)b * NPT * 3 + 1] = cy;
    new_xyz[(size_t)b * NPT * 3 + 2] = cz;
  }

  for (int t = 1; t < NPT; ++t) {
#pragma unroll
    for (int c = 0; c < 2; ++c) {
      float ex = fmaxf(fmaxf(bxmin[c] - cx, cx - bxmax[c]), 0.f);
      float ey = fmaxf(fmaxf(bymin[c] - cy, cy - bymax[c]), 0.f);
      float ez = fmaxf(fmaxf(bzmin[c] - cz, cz - bzmax[c]), 0.f);
      float dlb = (ex * ex + ey * ey + ez * ez) * 0.9999f;
      if (dlb < cmaxv[c]) {
        float mv = -1.0f; int mi = 1 << 30;
#pragma unroll
        for (int k = c * 8; k < c * 8 + 8; ++k) {
          float dx = px[k] - cx, dy = py[k] - cy, dz = pz[k] - cz;
          float d = __fadd_rn(__fadd_rn(__fmul_rn(dx, dx), __fmul_rn(dy, dy)), __fmul_rn(dz, dz));
          float dm = fminf(dmin[k], d);
          dmin[k] = dm;
          bool bet = (dm > mv) || (dm == mv && oid[k] < mi);
          mv = bet ? dm : mv;
          mi = bet ? oid[k] : mi;
        }
        cmaxv[c] = mv; cmaxi[c] = mi;
      }
    }
    // thread best = merge of 2 cluster bests (tie: min orig idx)
    float bestv = cmaxv[0]; int besti = cmaxi[0];
    {
      bool bet = (cmaxv[1] > bestv) || (cmaxv[1] == bestv && cmaxi[1] < besti);
      bestv = bet ? cmaxv[1] : bestv;
      besti = bet ? cmaxi[1] : besti;
    }

    // ---- slim two-stage wave reduction (all 32-bit) ----
    // stage 1: wave max of dist bits (dists >= 0 so uint order == float order)
    uint32_t vb = __float_as_uint(bestv);
    uint32_t rm = vb;
    DPP_ROR_U32_MAX(rm)   // 16-lane row max
    uint32_t m0 = (uint32_t)__builtin_amdgcn_readlane((int)rm, 0);
    uint32_t m1 = (uint32_t)__builtin_amdgcn_readlane((int)rm, 16);
    uint32_t m2 = (uint32_t)__builtin_amdgcn_readlane((int)rm, 32);
    uint32_t m3 = (uint32_t)__builtin_amdgcn_readlane((int)rm, 48);
    uint32_t wm = m0;
    if (m1 > wm) wm = m1;
    if (m2 > wm) wm = m2;
    if (m3 > wm) wm = m3;
    // stage 2: wave min index among lanes achieving wm
    uint32_t ik = (vb == wm) ? (uint32_t)besti : 0x7FFFFFFFu;
    DPP_ROR_U32_MIN(ik)
    uint32_t i0 = (uint32_t)__builtin_amdgcn_readlane((int)ik, 0);
    uint32_t i1 = (uint32_t)__builtin_amdgcn_readlane((int)ik, 16);
    uint32_t i2 = (uint32_t)__builtin_amdgcn_readlane((int)ik, 32);
    uint32_t i3 = (uint32_t)__builtin_amdgcn_readlane((int)ik, 48);
    uint32_t wi = i0;
    if (i1 < wi) wi = i1;
    if (i2 < wi) wi = i2;
    if (i3 < wi) wi = i3;

    uint64_t wkey = ((uint64_t)wm << 13) | (uint32_t)(8191u - wi);

    const int buf = t & 1;
    if (lane == 0) rec[buf][wv] = wkey;
    __syncthreads();

    uint64_t wk = rec[buf][0];
#pragma unroll
    for (int i = 1; i < 8; ++i) {
      uint64_t k = rec[buf][i];
      if (k > wk) wk = k;
    }

    int sidx = 8191 - (int)(wk & 8191u);
    sidx = __builtin_amdgcn_readfirstlane(sidx);   // force SGPR -> scalar loads
    const float* P = X + 3 * (size_t)sidx;
    cx = P[0]; cy = P[1]; cz = P[2];

    if (tid == 0) {
      float* o = new_xyz + ((size_t)b * NPT + t) * 3;
      o[0] = cx; o[1] = cy; o[2] = cz;
    }
  }
}

// ---------------- ball query: one wave per (b,s) ----------------
__global__ __launch_bounds__(256) void ballquery_kernel(const float* __restrict__ xyz,
                                                        const float* __restrict__ new_xyz,
                                                        int* __restrict__ idx_out) {
  const int w = blockIdx.x * 4 + (threadIdx.x >> 6);   // (b*2048 + s)
  const int lane = threadIdx.x & 63;
  const int b = w >> 11;
  const float* X = xyz + (size_t)b * NPTS * 3;
  const float cx = new_xyz[w * 3 + 0];
  const float cy = new_xyz[w * 3 + 1];
  const float cz = new_xyz[w * 3 + 2];
  int* out = idx_out + (size_t)w * NS;

  int found = 0;
  int first = -1;
  for (int base = 0; base < NPTS; base += 64) {
    const int p = base + lane;
    float x = X[p * 3 + 0], y = X[p * 3 + 1], z = X[p * 3 + 2];
    float dx = x - cx, dy = y - cy, dz = z - cz;
    float d2 = __fadd_rn(__fadd_rn(__fmul_rn(dx, dx), __fmul_rn(dy, dy)), __fmul_rn(dz, dz));
    unsigned long long mask = __ballot(d2 < R2);
    if (mask != 0ull && first < 0) first = base + __ffsll((unsigned long long)mask) - 1;
    if (found < NS) {
      if ((mask >> lane) & 1ull) {
        int rank = found + __popcll(mask & ((1ull << lane) - 1ull));
        if (rank < NS) out[rank] = p;
      }
    }
    found += __popcll(mask);
    if (found >= NS) break;
  }
  if (found < NS) {
    int pad = (first < 0) ? 0 : first;
    if (lane >= found && lane < NS) out[lane] = pad;
  }
}

// ---------------- group + MLP(67->128->256) + maxpool: one block per (b,s) ----------------
__global__ __launch_bounds__(256) void group_mlp_kernel(const float* __restrict__ xyz,
                                                        const float* __restrict__ feat,
                                                        const float* __restrict__ new_xyz,
                                                        const int* __restrict__ idx,
                                                        const float* __restrict__ w1t,
                                                        const float* __restrict__ b1,
                                                        const float* __restrict__ w2t,
                                                        const float* __restrict__ b2,
                                                        float* __restrict__ pooled) {
  const int blk = blockIdx.x;       // b*2048 + s
  const int b = blk >> 11, s = blk & 2047;
  const int tid = threadIdx.x;

  __shared__ __align__(16) float G[67 * 32];    // (C+3) x ns
  __shared__ __align__(16) float H1[128 * 32];  // 128 x ns
  __shared__ int   lidx[NS];
  __shared__ float ctr[3];

  if (tid < NS) lidx[tid] = idx[(size_t)blk * NS + tid];
  if (tid < 3)  ctr[tid] = new_xyz[blk * 3 + tid];
  __syncthreads();

  const float* F = feat + (size_t)b * CIN * NPTS;
  const float* X = xyz + (size_t)b * NPTS * 3;

  for (int e = tid; e < 67 * 32; e += 256) {
    int c = e >> 5, j = e & 31;
    int p = lidx[j];
    float v;
    if (c < 3) v = X[p * 3 + c] - ctr[c];
    else       v = F[(size_t)(c - 3) * NPTS + p];
    G[e] = v;
  }
  __syncthreads();

  // H1 = relu(W1 @ G + b1): 128x32, each thread 4o x 4j
  {
    const int oi = tid >> 3, ji = tid & 7;
    const int o0 = oi * 4, j0 = ji * 4;
    float acc[4][4];
#pragma unroll
    for (int i = 0; i < 4; ++i)
#pragma unroll
      for (int jj = 0; jj < 4; ++jj) acc[i][jj] = 0.f;
#pragma unroll 4
    for (int c = 0; c < 67; ++c) {
      float4 g  = *(const float4*)&G[c * 32 + j0];
      float4 wf = *(const float4*)&w1t[c * 128 + o0];
      float ga[4] = {g.x, g.y, g.z, g.w};
      float wa[4] = {wf.x, wf.y, wf.z, wf.w};
#pragma unroll
      for (int i = 0; i < 4; ++i)
#pragma unroll
        for (int jj = 0; jj < 4; ++jj)
          acc[i][jj] = fmaf(wa[i], ga[jj], acc[i][jj]);
    }
    float4 bb = *(const float4*)&b1[o0];
    float ba[4] = {bb.x, bb.y, bb.z, bb.w};
#pragma unroll
    for (int i = 0; i < 4; ++i) {
      float4 h;
      h.x = fmaxf(acc[i][0] + ba[i], 0.f);
      h.y = fmaxf(acc[i][1] + ba[i], 0.f);
      h.z = fmaxf(acc[i][2] + ba[i], 0.f);
      h.w = fmaxf(acc[i][3] + ba[i], 0.f);
      *(float4*)&H1[(o0 + i) * 32 + j0] = h;
    }
  }
  __syncthreads();

  // H2 = relu(W2 @ H1 + b2): 256x32, each thread 8o x 4j, then maxpool over j
  {
    const int oi = tid >> 3, ji = tid & 7;
    const int o0 = oi * 8, j0 = ji * 4;
    float acc[8][4];
#pragma unroll
    for (int i = 0; i < 8; ++i)
#pragma unroll
      for (int jj = 0; jj < 4; ++jj) acc[i][jj] = 0.f;
#pragma unroll 2
    for (int c = 0; c < 128; ++c) {
      float4 h  = *(const float4*)&H1[c * 32 + j0];
      float4 wa4 = *(const float4*)&w2t[c * 256 + o0];
      float4 wb4 = *(const float4*)&w2t[c * 256 + o0 + 4];
      float ha[4] = {h.x, h.y, h.z, h.w};
      float wa[8] = {wa4.x, wa4.y, wa4.z, wa4.w, wb4.x, wb4.y, wb4.z, wb4.w};
#pragma unroll
      for (int i = 0; i < 8; ++i)
#pragma unroll
        for (int jj = 0; jj < 4; ++jj)
          acc[i][jj] = fmaf(wa[i], ha[jj], acc[i][jj]);
    }
    float4 b2a = *(const float4*)&b2[o0];
    float4 b2b = *(const float4*)&b2[o0 + 4];
    float bb[8] = {b2a.x, b2a.y, b2a.z, b2a.w, b2b.x, b2b.y, b2b.z, b2b.w};
    float m[8];
#pragma unroll
    for (int i = 0; i < 8; ++i) {
      float v0 = fmaxf(acc[i][0] + bb[i], 0.f);
      float v1 = fmaxf(acc[i][1] + bb[i], 0.f);
      float v2 = fmaxf(acc[i][2] + bb[i], 0.f);
      float v3 = fmaxf(acc[i][3] + bb[i], 0.f);
      m[i] = fmaxf(fmaxf(v0, v1), fmaxf(v2, v3));
    }
#pragma unroll
    for (int off = 1; off < 8; off <<= 1)
#pragma unroll
      for (int i = 0; i < 8; ++i) m[i] = fmaxf(m[i], __shfl_xor(m[i], off));
    if (ji == 0) {
#pragma unroll
      for (int i = 0; i < 8; ++i)
        pooled[((size_t)b * 256 + o0 + i) * (size_t)NPT + s] = m[i];
    }
  }
}

extern "C" void kernel_launch(void* const* d_in, const int* in_sizes, int n_in,
                              void* d_out, int out_size, void* d_ws, size_t ws_size,
                              hipStream_t stream) {
  (void)in_sizes; (void)n_in; (void)out_size; (void)ws_size;
  const float* xyz  = (const float*)d_in[0];   // (4,8192,3)
  const float* feat = (const float*)d_in[1];   // (4,64,8192)
  const float* w1   = (const float*)d_in[2];   // (128,67)
  const float* b1   = (const float*)d_in[3];   // (128)
  const float* w2   = (const float*)d_in[4];   // (256,128)
  const float* b2   = (const float*)d_in[5];   // (256)

  float* out     = (float*)d_out;
  float* new_xyz = out;                        // (4,2048,3)
  float* pooled  = out + (size_t)BATCH * NPT * 3;  // (4,256,2048)

  char* ws = (char*)d_ws;
  float*  w1t    = (float*)ws;                         // 34304 B
  float*  w2t    = (float*)(ws + 34304);               // 131072 B
  int*    idx    = (int*)(ws + 34304 + 131072);        // 1048576 B
  float4* sorted = (float4*)(ws + 34304 + 131072 + 1048576);  // 524288 B (16B-aligned)

  prep_kernel<<<128, 256, 0, stream>>>(w1, w2, w1t, w2t);
  sort_kernel<<<BATCH, 1024, 0, stream>>>(xyz, sorted);
  fps_kernel<<<BATCH, 512, 0, stream>>>(xyz, sorted, new_xyz);
  ballquery_kernel<<<(BATCH * NPT) / 4, 256, 0, stream>>>(xyz, new_xyz, idx);
  group_mlp_kernel<<<BATCH * NPT, 256, 0, stream>>>(xyz, feat, new_xyz, idx,
                                                    w1t, b1, w2t, b2, pooled);
}

// Round 6
// 2197.781 us; speedup vs baseline: 2.7866x; 1.7870x over previous
//
#include <hip/hip_runtime.h>

// Problem constants (from reference)
#define NPTS   8192   // N
#define NPT    2048   // NPOINT
#define NS     32     // NSAMPLE
#define CIN    64
#define BATCH  4
// threshold: f32 nearest to 0.64 (numpy/jax weak-type the python float 0.8**2 to f32)
#define R2     0.64f

// ---------------- prep: transpose weights into ws ----------------
__global__ __launch_bounds__(256) void prep_kernel(const float* __restrict__ w1,
                                                   const float* __restrict__ w2,
                                                   float* __restrict__ w1t,
                                                   float* __restrict__ w2t) {
  int i = blockIdx.x * 256 + threadIdx.x;
  if (i < 128 * 67) {
    int o = i / 67, c = i % 67;
    w1t[c * 128 + o] = w1[i];
  }
  if (i < 256 * 128) {
    int o = i >> 7, c = i & 127;
    w2t[c * 256 + o] = w2[i];
  }
}

// ---------------- Morton sort (u32 keys, in-LDS bitonic) ----------------
__device__ inline uint32_t part1by2(uint32_t x) {
  x &= 1023u;
  x = (x | (x << 16)) & 0x030000FFu;
  x = (x | (x << 8))  & 0x0300F00Fu;
  x = (x | (x << 4))  & 0x030C30C3u;
  x = (x | (x << 2))  & 0x09249249u;
  return x;
}

__device__ inline uint32_t morton3(float x, float y, float z) {
  int qx = (int)((x + 16.f) * 32.f);
  int qy = (int)((y + 16.f) * 32.f);
  int qz = (int)((z + 16.f) * 32.f);
  qx = qx < 0 ? 0 : (qx > 1023 ? 1023 : qx);
  qy = qy < 0 ? 0 : (qy > 1023 ? 1023 : qy);
  qz = qz < 0 ? 0 : (qz > 1023 ? 1023 : qz);
  return part1by2((uint32_t)qx) | (part1by2((uint32_t)qy) << 1) | (part1by2((uint32_t)qz) << 2);
}

// key = (morton top 19 bits << 13) | idx. Sort order only affects clustering
// quality, never correctness (min-updates are exact & order-independent).
__global__ __launch_bounds__(1024) void sort_kernel(const float* __restrict__ xyz,
                                                    float4* __restrict__ sorted) {
  const int b = blockIdx.x;
  const int tid = threadIdx.x;
  const float* X = xyz + (size_t)b * NPTS * 3;
  __shared__ uint32_t S[NPTS];  // 32 KB

  for (int k = 0; k < 8; ++k) {
    int p = tid + (k << 10);
    uint32_t m = morton3(X[p * 3 + 0], X[p * 3 + 1], X[p * 3 + 2]);
    S[p] = ((m >> 11) << 13) | (uint32_t)p;
  }
  __syncthreads();
  for (unsigned k = 2; k <= NPTS; k <<= 1) {
    for (unsigned j = k >> 1; j > 0; j >>= 1) {
      for (int i = tid; i < NPTS; i += 1024) {
        int l = i ^ (int)j;
        if (l > i) {
          uint32_t a = S[i], c = S[l];
          bool sw = ((i & k) == 0) ? (a > c) : (a < c);
          if (sw) { S[i] = c; S[l] = a; }
        }
      }
      __syncthreads();
    }
  }
  for (int k = 0; k < 8; ++k) {
    int pos = tid + (k << 10);
    int o = (int)(S[pos] & 8191u);
    float4 v;
    v.x = X[o * 3 + 0]; v.y = X[o * 3 + 1]; v.z = X[o * 3 + 2];
    v.w = __int_as_float(o);
    sorted[(size_t)b * NPTS + pos] = v;
  }
}

// ---------------- FPS v6: 1024 thr x 8 pts (no-spill envelope) + pruning +
//                  slim u32 two-stage reduction ----------------
// Bit-exactness (same arguments verified absmax 0.0 in R2/R3):
//  * min-updates use exact-rounded ((dx*dx+dy*dy)+dz*dz); order-independent.
//  * cluster skipped only if 0.9999-scaled conservative bbox lower bound
//    >= cluster max dmin; fp analysis: computed d >= D_true*(1-2e-7),
//    dlb <= B_true*0.99993, D_true >= B_true -> d >= dmin for all cluster
//    points whenever the skip fires (B=0 case: cmaxv<=0 -> all dmin 0, no-op).
//  * all dists are nonneg f32 (+0 only), so u32 order == float order.
//  * tie-breaks -> smallest original index at every stage (numpy argmax):
//    thread points pre-sorted by oid (strict > keeps first), wave/block pick
//    min index among value-matching candidates.

#define DPP_ROR_U32_MAX(v)                                                       \
  {                                                                              \
    uint32_t _t;                                                                 \
    _t = (uint32_t)__builtin_amdgcn_update_dpp(0, (int)(v), 0x121, 0xF, 0xF, false); if (_t > (v)) (v) = _t; \
    _t = (uint32_t)__builtin_amdgcn_update_dpp(0, (int)(v), 0x122, 0xF, 0xF, false); if (_t > (v)) (v) = _t; \
    _t = (uint32_t)__builtin_amdgcn_update_dpp(0, (int)(v), 0x124, 0xF, 0xF, false); if (_t > (v)) (v) = _t; \
    _t = (uint32_t)__builtin_amdgcn_update_dpp(0, (int)(v), 0x128, 0xF, 0xF, false); if (_t > (v)) (v) = _t; \
  }

#define DPP_ROR_U32_MIN(v)                                                       \
  {                                                                              \
    uint32_t _t;                                                                 \
    _t = (uint32_t)__builtin_amdgcn_update_dpp(-1, (int)(v), 0x121, 0xF, 0xF, false); if (_t < (v)) (v) = _t; \
    _t = (uint32_t)__builtin_amdgcn_update_dpp(-1, (int)(v), 0x122, 0xF, 0xF, false); if (_t < (v)) (v) = _t; \
    _t = (uint32_t)__builtin_amdgcn_update_dpp(-1, (int)(v), 0x124, 0xF, 0xF, false); if (_t < (v)) (v) = _t; \
    _t = (uint32_t)__builtin_amdgcn_update_dpp(-1, (int)(v), 0x128, 0xF, 0xF, false); if (_t < (v)) (v) = _t; \
  }

#define CSWAP(i, j)                                                              \
  if (oid[i] > oid[j]) {                                                         \
    int _ti = oid[i]; oid[i] = oid[j]; oid[j] = _ti;                             \
    float _tf;                                                                   \
    _tf = px[i]; px[i] = px[j]; px[j] = _tf;                                     \
    _tf = py[i]; py[i] = py[j]; py[j] = _tf;                                     \
    _tf = pz[i]; pz[i] = pz[j]; pz[j] = _tf;                                     \
  }

__global__ __launch_bounds__(1024) void fps_kernel(const float* __restrict__ xyz,
                                                   const float4* __restrict__ sorted,
                                                   float* __restrict__ new_xyz) {
  const int b = blockIdx.x;
  const int tid = threadIdx.x;     // 0..1023
  const int lane = tid & 63;
  const int wv = tid >> 6;         // 0..15
  const float* X = xyz + (size_t)b * NPTS * 3;
  const float4* SP = sorted + (size_t)b * NPTS;

  __shared__ __align__(8) uint2 rec[2][16];

  // own 8 CONTIGUOUS morton-sorted points (one spatial cluster per thread)
  float px[8], py[8], pz[8], dmin[8];
  int oid[8];
#pragma unroll
  for (int k = 0; k < 8; ++k) {
    float4 p = SP[tid * 8 + k];
    px[k] = p.x; py[k] = p.y; pz[k] = p.z;
    oid[k] = __float_as_int(p.w);
    dmin[k] = 1e10f;
  }
  // sort the 8 points by original index (Batcher 19-comparator network) so the
  // burst argmax tie-break is a strict '>' (first max == smallest oid).
  CSWAP(0, 1) CSWAP(2, 3) CSWAP(4, 5) CSWAP(6, 7)
  CSWAP(0, 2) CSWAP(1, 3) CSWAP(4, 6) CSWAP(5, 7)
  CSWAP(1, 2) CSWAP(5, 6)
  CSWAP(0, 4) CSWAP(1, 5) CSWAP(2, 6) CSWAP(3, 7)
  CSWAP(2, 4) CSWAP(3, 5)
  CSWAP(1, 2) CSWAP(3, 4) CSWAP(5, 6)

  // cluster bbox (membership unchanged by the oid re-sort)
  float bxmin = px[0], bxmax = px[0], bymin = py[0], bymax = py[0], bzmin = pz[0], bzmax = pz[0];
#pragma unroll
  for (int k = 1; k < 8; ++k) {
    bxmin = fminf(bxmin, px[k]); bxmax = fmaxf(bxmax, px[k]);
    bymin = fminf(bymin, py[k]); bymax = fmaxf(bymax, py[k]);
    bzmin = fminf(bzmin, pz[k]); bzmax = fmaxf(bzmax, pz[k]);
  }
  float cmaxv = 1e10f;   // forces full update at t=1 (dlb << 1e10)
  int   cmaxi = oid[0];

  float cx = X[0], cy = X[1], cz = X[2];
  if (tid == 0) {
    new_xyz[(size_t)b * NPT * 3 + 0] = cx;
    new_xyz[(size_t)b * NPT * 3 + 1] = cy;
    new_xyz[(size_t)b * NPT * 3 + 2] = cz;
  }

  for (int t = 1; t < NPT; ++t) {
    // conservative lower bound of squared dist from center to cluster bbox
    float ex = fmaxf(fmaxf(bxmin - cx, cx - bxmax), 0.f);
    float ey = fmaxf(fmaxf(bymin - cy, cy - bymax), 0.f);
    float ez = fmaxf(fmaxf(bzmin - cz, cz - bzmax), 0.f);
    float dlb = (ex * ex + ey * ey + ez * ez) * 0.9999f;
    if (dlb < cmaxv) {
      float mv = -1.0f; int mi = 0;
#pragma unroll
      for (int k = 0; k < 8; ++k) {
        float dx = px[k] - cx, dy = py[k] - cy, dz = pz[k] - cz;
        float d = __fadd_rn(__fadd_rn(__fmul_rn(dx, dx), __fmul_rn(dy, dy)), __fmul_rn(dz, dz));
        float dm = fminf(dmin[k], d);
        dmin[k] = dm;
        if (dm > mv) { mv = dm; mi = oid[k]; }   // strict > : first max = min oid
      }
      cmaxv = mv; cmaxi = mi;
    }

    // ---- wave reduction, all 32-bit, value stage then index stage ----
    uint32_t vb = __float_as_uint(cmaxv);
    uint32_t rm = vb;
    DPP_ROR_U32_MAX(rm)   // every lane: max of its 16-lane row
    uint32_t m0 = (uint32_t)__builtin_amdgcn_readlane((int)rm, 0);
    uint32_t m1 = (uint32_t)__builtin_amdgcn_readlane((int)rm, 16);
    uint32_t m2 = (uint32_t)__builtin_amdgcn_readlane((int)rm, 32);
    uint32_t m3 = (uint32_t)__builtin_amdgcn_readlane((int)rm, 48);
    uint32_t wm = m0 > m1 ? m0 : m1;
    uint32_t wmb = m2 > m3 ? m2 : m3;
    wm = wm > wmb ? wm : wmb;                  // scalar (uniform) merges
    uint32_t ik = (vb == wm) ? (uint32_t)cmaxi : 0xFFFFFFFFu;
    DPP_ROR_U32_MIN(ik)
    uint32_t i0 = (uint32_t)__builtin_amdgcn_readlane((int)ik, 0);
    uint32_t i1 = (uint32_t)__builtin_amdgcn_readlane((int)ik, 16);
    uint32_t i2 = (uint32_t)__builtin_amdgcn_readlane((int)ik, 32);
    uint32_t i3 = (uint32_t)__builtin_amdgcn_readlane((int)ik, 48);
    uint32_t wi = i0 < i1 ? i0 : i1;
    uint32_t wib = i2 < i3 ? i2 : i3;
    wi = wi < wib ? wi : wib;

    const int buf = t & 1;
    if (lane == 0) { rec[buf][wv].x = wm; rec[buf][wv].y = wi; }
    __syncthreads();

    // ---- block stage: 16 wave-winners, same two-stage trick ----
    uint2 r = rec[buf][lane & 15];
    uint32_t bm = r.x;
    DPP_ROR_U32_MAX(bm)                        // block max (rows replicate)
    uint32_t ci = (r.x == bm) ? r.y : 0xFFFFFFFFu;
    DPP_ROR_U32_MIN(ci)                        // min idx among matching waves
    int sidx = __builtin_amdgcn_readfirstlane((int)ci);

    const float* P = X + 3 * (size_t)sidx;     // uniform -> scalar loads
    cx = P[0]; cy = P[1]; cz = P[2];

    if (tid == 0) {
      float* o = new_xyz + ((size_t)b * NPT + t) * 3;
      o[0] = cx; o[1] = cy; o[2] = cz;
    }
  }
}

// ---------------- ball query: one wave per (b,s) ----------------
__global__ __launch_bounds__(256) void ballquery_kernel(const float* __restrict__ xyz,
                                                        const float* __restrict__ new_xyz,
                                                        int* __restrict__ idx_out) {
  const int w = blockIdx.x * 4 + (threadIdx.x >> 6);   // (b*2048 + s)
  const int lane = threadIdx.x & 63;
  const int b = w >> 11;
  const float* X = xyz + (size_t)b * NPTS * 3;
  const float cx = new_xyz[w * 3 + 0];
  const float cy = new_xyz[w * 3 + 1];
  const float cz = new_xyz[w * 3 + 2];
  int* out = idx_out + (size_t)w * NS;

  int found = 0;
  int first = -1;
  for (int base = 0; base < NPTS; base += 64) {
    const int p = base + lane;
    float x = X[p * 3 + 0], y = X[p * 3 + 1], z = X[p * 3 + 2];
    float dx = x - cx, dy = y - cy, dz = z - cz;
    float d2 = __fadd_rn(__fadd_rn(__fmul_rn(dx, dx), __fmul_rn(dy, dy)), __fmul_rn(dz, dz));
    unsigned long long mask = __ballot(d2 < R2);
    if (mask != 0ull && first < 0) first = base + __ffsll((unsigned long long)mask) - 1;
    if (found < NS) {
      if ((mask >> lane) & 1ull) {
        int rank = found + __popcll(mask & ((1ull << lane) - 1ull));
        if (rank < NS) out[rank] = p;
      }
    }
    found += __popcll(mask);
    if (found >= NS) break;
  }
  if (found < NS) {
    int pad = (first < 0) ? 0 : first;
    if (lane >= found && lane < NS) out[lane] = pad;
  }
}

// ---------------- group + MLP(67->128->256) + maxpool: one block per (b,s) ----------------
__global__ __launch_bounds__(256) void group_mlp_kernel(const float* __restrict__ xyz,
                                                        const float* __restrict__ feat,
                                                        const float* __restrict__ new_xyz,
                                                        const int* __restrict__ idx,
                                                        const float* __restrict__ w1t,
                                                        const float* __restrict__ b1,
                                                        const float* __restrict__ w2t,
                                                        const float* __restrict__ b2,
                                                        float* __restrict__ pooled) {
  const int blk = blockIdx.x;       // b*2048 + s
  const int b = blk >> 11, s = blk & 2047;
  const int tid = threadIdx.x;

  __shared__ __align__(16) float G[67 * 32];    // (C+3) x ns
  __shared__ __align__(16) float H1[128 * 32];  // 128 x ns
  __shared__ int   lidx[NS];
  __shared__ float ctr[3];

  if (tid < NS) lidx[tid] = idx[(size_t)blk * NS + tid];
  if (tid < 3)  ctr[tid] = new_xyz[blk * 3 + tid];
  __syncthreads();

  const float* F = feat + (size_t)b * CIN * NPTS;
  const float* X = xyz + (size_t)b * NPTS * 3;

  for (int e = tid; e < 67 * 32; e += 256) {
    int c = e >> 5, j = e & 31;
    int p = lidx[j];
    float v;
    if (c < 3) v = X[p * 3 + c] - ctr[c];
    else       v = F[(size_t)(c - 3) * NPTS + p];
    G[e] = v;
  }
  __syncthreads();

  // H1 = relu(W1 @ G + b1): 128x32, each thread 4o x 4j
  {
    const int oi = tid >> 3, ji = tid & 7;
    const int o0 = oi * 4, j0 = ji * 4;
    float acc[4][4];
#pragma unroll
    for (int i = 0; i < 4; ++i)
#pragma unroll
      for (int jj = 0; jj < 4; ++jj) acc[i][jj] = 0.f;
#pragma unroll 4
    for (int c = 0; c < 67; ++c) {
      float4 g  = *(const float4*)&G[c * 32 + j0];
      float4 wf = *(const float4*)&w1t[c * 128 + o0];
      float ga[4] = {g.x, g.y, g.z, g.w};
      float wa[4] = {wf.x, wf.y, wf.z, wf.w};
#pragma unroll
      for (int i = 0; i < 4; ++i)
#pragma unroll
        for (int jj = 0; jj < 4; ++jj)
          acc[i][jj] = fmaf(wa[i], ga[jj], acc[i][jj]);
    }
    float4 bb = *(const float4*)&b1[o0];
    float ba[4] = {bb.x, bb.y, bb.z, bb.w};
#pragma unroll
    for (int i = 0; i < 4; ++i) {
      float4 h;
      h.x = fmaxf(acc[i][0] + ba[i], 0.f);
      h.y = fmaxf(acc[i][1] + ba[i], 0.f);
      h.z = fmaxf(acc[i][2] + ba[i], 0.f);
      h.w = fmaxf(acc[i][3] + ba[i], 0.f);
      *(float4*)&H1[(o0 + i) * 32 + j0] = h;
    }
  }
  __syncthreads();

  // H2 = relu(W2 @ H1 + b2): 256x32, each thread 8o x 4j, then maxpool over j
  {
    const int oi = tid >> 3, ji = tid & 7;
    const int o0 = oi * 8, j0 = ji * 4;
    float acc[8][4];
#pragma unroll
    for (int i = 0; i < 8; ++i)
#pragma unroll
      for (int jj = 0; jj < 4; ++jj) acc[i][jj] = 0.f;
#pragma unroll 2
    for (int c = 0; c < 128; ++c) {
      float4 h  = *(const float4*)&H1[c * 32 + j0];
      float4 wa4 = *(const float4*)&w2t[c * 256 + o0];
      float4 wb4 = *(const float4*)&w2t[c * 256 + o0 + 4];
      float ha[4] = {h.x, h.y, h.z, h.w};
      float wa[8] = {wa4.x, wa4.y, wa4.z, wa4.w, wb4.x, wb4.y, wb4.z, wb4.w};
#pragma unroll
      for (int i = 0; i < 8; ++i)
#pragma unroll
        for (int jj = 0; jj < 4; ++jj)
          acc[i][jj] = fmaf(wa[i], ha[jj], acc[i][jj]);
    }
    float4 b2a = *(const float4*)&b2[o0];
    float4 b2b = *(const float4*)&b2[o0 + 4];
    float bb[8] = {b2a.x, b2a.y, b2a.z, b2a.w, b2b.x, b2b.y, b2b.z, b2b.w};
    float m[8];
#pragma unroll
    for (int i = 0; i < 8; ++i) {
      float v0 = fmaxf(acc[i][0] + bb[i], 0.f);
      float v1 = fmaxf(acc[i][1] + bb[i], 0.f);
      float v2 = fmaxf(acc[i][2] + bb[i], 0.f);
      float v3 = fmaxf(acc[i][3] + bb[i], 0.f);
      m[i] = fmaxf(fmaxf(v0, v1), fmaxf(v2, v3));
    }
#pragma unroll
    for (int off = 1; off < 8; off <<= 1)
#pragma unroll
      for (int i = 0; i < 8; ++i) m[i] = fmaxf(m[i], __shfl_xor(m[i], off));
    if (ji == 0) {
#pragma unroll
      for (int i = 0; i < 8; ++i)
        pooled[((size_t)b * 256 + o0 + i) * (size_t)NPT + s] = m[i];
    }
  }
}

extern "C" void kernel_launch(void* const* d_in, const int* in_sizes, int n_in,
                              void* d_out, int out_size, void* d_ws, size_t ws_size,
                              hipStream_t stream) {
  (void)in_sizes; (void)n_in; (void)out_size; (void)ws_size;
  const float* xyz  = (const float*)d_in[0];   // (4,8192,3)
  const float* feat = (const float*)d_in[1];   // (4,64,8192)
  const float* w1   = (const float*)d_in[2];   // (128,67)
  const float* b1   = (const float*)d_in[3];   // (128)
  const float* w2   = (const float*)d_in[4];   // (256,128)
  const float* b2   = (const float*)d_in[5];   // (256)

  float* out     = (float*)d_out;
  float* new_xyz = out;                        // (4,2048,3)
  float* pooled  = out + (size_t)BATCH * NPT * 3;  // (4,256,2048)

  char* ws = (char*)d_ws;
  float*  w1t    = (float*)ws;                         // 34304 B
  float*  w2t    = (float*)(ws + 34304);               // 131072 B
  int*    idx    = (int*)(ws + 34304 + 131072);        // 1048576 B
  float4* sorted = (float4*)(ws + 34304 + 131072 + 1048576);  // 524288 B (16B-aligned)

  prep_kernel<<<128, 256, 0, stream>>>(w1, w2, w1t, w2t);
  sort_kernel<<<BATCH, 1024, 0, stream>>>(xyz, sorted);
  fps_kernel<<<BATCH, 1024, 0, stream>>>(xyz, sorted, new_xyz);
  ballquery_kernel<<<(BATCH * NPT) / 4, 256, 0, stream>>>(xyz, new_xyz, idx);
  group_mlp_kernel<<<BATCH * NPT, 256, 0, stream>>>(xyz, feat, new_xyz, idx,
                                                    w1t, b1, w2t, b2, pooled);
}

// Round 7
// 1938.796 us; speedup vs baseline: 3.1588x; 1.1336x over previous
//
#include <hip/hip_runtime.h>

// Problem constants (from reference)
#define NPTS   8192   // N
#define NPT    2048   // NPOINT
#define NS     32     // NSAMPLE
#define CIN    64
#define BATCH  4
// threshold: f32 nearest to 0.64 (numpy/jax weak-type the python float 0.8**2 to f32)
#define R2     0.64f

// ---------------- prep: transpose weights into ws ----------------
__global__ __launch_bounds__(256) void prep_kernel(const float* __restrict__ w1,
                                                   const float* __restrict__ w2,
                                                   float* __restrict__ w1t,
                                                   float* __restrict__ w2t) {
  int i = blockIdx.x * 256 + threadIdx.x;
  if (i < 128 * 67) {
    int o = i / 67, c = i % 67;
    w1t[c * 128 + o] = w1[i];
  }
  if (i < 256 * 128) {
    int o = i >> 7, c = i & 127;
    w2t[c * 256 + o] = w2[i];
  }
}

// ---------------- Morton sort (u32 keys, in-LDS bitonic) ----------------
__device__ inline uint32_t part1by2(uint32_t x) {
  x &= 1023u;
  x = (x | (x << 16)) & 0x030000FFu;
  x = (x | (x << 8))  & 0x0300F00Fu;
  x = (x | (x << 4))  & 0x030C30C3u;
  x = (x | (x << 2))  & 0x09249249u;
  return x;
}

__device__ inline uint32_t morton3(float x, float y, float z) {
  int qx = (int)((x + 16.f) * 32.f);
  int qy = (int)((y + 16.f) * 32.f);
  int qz = (int)((z + 16.f) * 32.f);
  qx = qx < 0 ? 0 : (qx > 1023 ? 1023 : qx);
  qy = qy < 0 ? 0 : (qy > 1023 ? 1023 : qy);
  qz = qz < 0 ? 0 : (qz > 1023 ? 1023 : qz);
  return part1by2((uint32_t)qx) | (part1by2((uint32_t)qy) << 1) | (part1by2((uint32_t)qz) << 2);
}

// key = (morton top 19 bits << 13) | idx. Sort order only affects clustering
// quality, never correctness (min-updates are exact & order-independent).
__global__ __launch_bounds__(1024) void sort_kernel(const float* __restrict__ xyz,
                                                    float4* __restrict__ sorted) {
  const int b = blockIdx.x;
  const int tid = threadIdx.x;
  const float* X = xyz + (size_t)b * NPTS * 3;
  __shared__ uint32_t S[NPTS];  // 32 KB

  for (int k = 0; k < 8; ++k) {
    int p = tid + (k << 10);
    uint32_t m = morton3(X[p * 3 + 0], X[p * 3 + 1], X[p * 3 + 2]);
    S[p] = ((m >> 11) << 13) | (uint32_t)p;
  }
  __syncthreads();
  for (unsigned k = 2; k <= NPTS; k <<= 1) {
    for (unsigned j = k >> 1; j > 0; j >>= 1) {
      for (int i = tid; i < NPTS; i += 1024) {
        int l = i ^ (int)j;
        if (l > i) {
          uint32_t a = S[i], c = S[l];
          bool sw = ((i & k) == 0) ? (a > c) : (a < c);
          if (sw) { S[i] = c; S[l] = a; }
        }
      }
      __syncthreads();
    }
  }
  for (int k = 0; k < 8; ++k) {
    int pos = tid + (k << 10);
    int o = (int)(S[pos] & 8191u);
    float4 v;
    v.x = X[o * 3 + 0]; v.y = X[o * 3 + 1]; v.z = X[o * 3 + 2];
    v.w = __int_as_float(o);
    sorted[(size_t)b * NPTS + pos] = v;
  }
}

// ---------------- FPS v7: v6 + cached wave-reduce + LDS coords + ballot idx ----
// Bit-exactness (verified absmax 0.0 in R2/R3/R6 with same math):
//  * min-updates use exact-rounded ((dx*dx+dy*dy)+dz*dz); order-independent.
//  * cluster skipped only if 0.9999-scaled conservative bbox lower bound
//    >= cluster max dmin -> skip provably a no-op (1e-4 margin >> 2e-7 rounding).
//  * cached wave (wm,wi) reused only when NO lane of the wave ran a burst ->
//    no cmaxv/cmaxi in the wave changed -> wave reduction result identical.
//    Winner's cluster self-activates next iter (center inside bbox -> dlb=0);
//    cmaxv==0 clusters are immutable (all dmin already 0), skip is safe.
//  * all dists nonneg f32, so u32 order == float order.
//  * tie-breaks -> smallest original index at every stage (numpy argmax):
//    thread points pre-sorted by oid (strict > keeps first); wave index stage
//    takes min oid among value-matching lanes (ballot fast path when unique,
//    exact DPP-min fallback); block stage min oid among matching waves.

#define DPP_ROR_U32_MAX(v)                                                       \
  {                                                                              \
    uint32_t _t;                                                                 \
    _t = (uint32_t)__builtin_amdgcn_update_dpp(0, (int)(v), 0x121, 0xF, 0xF, false); if (_t > (v)) (v) = _t; \
    _t = (uint32_t)__builtin_amdgcn_update_dpp(0, (int)(v), 0x122, 0xF, 0xF, false); if (_t > (v)) (v) = _t; \
    _t = (uint32_t)__builtin_amdgcn_update_dpp(0, (int)(v), 0x124, 0xF, 0xF, false); if (_t > (v)) (v) = _t; \
    _t = (uint32_t)__builtin_amdgcn_update_dpp(0, (int)(v), 0x128, 0xF, 0xF, false); if (_t > (v)) (v) = _t; \
  }

#define DPP_ROR_U32_MIN(v)                                                       \
  {                                                                              \
    uint32_t _t;                                                                 \
    _t = (uint32_t)__builtin_amdgcn_update_dpp(-1, (int)(v), 0x121, 0xF, 0xF, false); if (_t < (v)) (v) = _t; \
    _t = (uint32_t)__builtin_amdgcn_update_dpp(-1, (int)(v), 0x122, 0xF, 0xF, false); if (_t < (v)) (v) = _t; \
    _t = (uint32_t)__builtin_amdgcn_update_dpp(-1, (int)(v), 0x124, 0xF, 0xF, false); if (_t < (v)) (v) = _t; \
    _t = (uint32_t)__builtin_amdgcn_update_dpp(-1, (int)(v), 0x128, 0xF, 0xF, false); if (_t < (v)) (v) = _t; \
  }

#define CSWAP(i, j)                                                              \
  if (oid[i] > oid[j]) {                                                         \
    int _ti = oid[i]; oid[i] = oid[j]; oid[j] = _ti;                             \
    float _tf;                                                                   \
    _tf = px[i]; px[i] = px[j]; px[j] = _tf;                                     \
    _tf = py[i]; py[i] = py[j]; py[j] = _tf;                                     \
    _tf = pz[i]; pz[i] = pz[j]; pz[j] = _tf;                                     \
  }

__global__ __launch_bounds__(1024) void fps_kernel(const float* __restrict__ xyz,
                                                   const float4* __restrict__ sorted,
                                                   float* __restrict__ new_xyz) {
  const int b = blockIdx.x;
  const int tid = threadIdx.x;     // 0..1023
  const int lane = tid & 63;
  const int wv = tid >> 6;         // 0..15
  const float* X = xyz + (size_t)b * NPTS * 3;
  const float4* SP = sorted + (size_t)b * NPTS;

  __shared__ float XL[NPTS * 3];          // 96 KB coord table (winner lookup)
  __shared__ __align__(8) uint2 rec[2][16];

  // stage coords into LDS (coalesced; read-only in the loop)
  for (int i = tid; i < NPTS * 3; i += 1024) XL[i] = X[i];

  // own 8 CONTIGUOUS morton-sorted points (one spatial cluster per thread)
  float px[8], py[8], pz[8], dmin[8];
  int oid[8];
#pragma unroll
  for (int k = 0; k < 8; ++k) {
    float4 p = SP[tid * 8 + k];
    px[k] = p.x; py[k] = p.y; pz[k] = p.z;
    oid[k] = __float_as_int(p.w);
    dmin[k] = 1e10f;
  }
  // sort the 8 points by original index (Batcher 19-comparator network) so the
  // burst argmax tie-break is a strict '>' (first max == smallest oid).
  CSWAP(0, 1) CSWAP(2, 3) CSWAP(4, 5) CSWAP(6, 7)
  CSWAP(0, 2) CSWAP(1, 3) CSWAP(4, 6) CSWAP(5, 7)
  CSWAP(1, 2) CSWAP(5, 6)
  CSWAP(0, 4) CSWAP(1, 5) CSWAP(2, 6) CSWAP(3, 7)
  CSWAP(2, 4) CSWAP(3, 5)
  CSWAP(1, 2) CSWAP(3, 4) CSWAP(5, 6)

  // cluster bbox
  float bxmin = px[0], bxmax = px[0], bymin = py[0], bymax = py[0], bzmin = pz[0], bzmax = pz[0];
#pragma unroll
  for (int k = 1; k < 8; ++k) {
    bxmin = fminf(bxmin, px[k]); bxmax = fmaxf(bxmax, px[k]);
    bymin = fminf(bymin, py[k]); bymax = fmaxf(bymax, py[k]);
    bzmin = fminf(bzmin, pz[k]); bzmax = fmaxf(bzmax, pz[k]);
  }
  float cmaxv = 1e10f;   // forces full update at t=1 (dlb << 1e10)
  int   cmaxi = oid[0];

  // cached wave-winner (valid after first iteration; t=1 always recomputes)
  uint32_t wwm = 0u, wwi = 0u;

  float cx = X[0], cy = X[1], cz = X[2];
  if (tid == 0) {
    new_xyz[(size_t)b * NPT * 3 + 0] = cx;
    new_xyz[(size_t)b * NPT * 3 + 1] = cy;
    new_xyz[(size_t)b * NPT * 3 + 2] = cz;
  }
  __syncthreads();   // XL ready

  for (int t = 1; t < NPT; ++t) {
    // conservative lower bound of squared dist from center to cluster bbox
    float ex = __builtin_amdgcn_fmed3f(bxmin - cx, cx - bxmax, 1e30f);  // max of 2 nonpos-capable
    ex = fmaxf(ex, 0.f);
    float ey = fmaxf(fmaxf(bymin - cy, cy - bymax), 0.f);
    float ez = fmaxf(fmaxf(bzmin - cz, cz - bzmax), 0.f);
    ex = fmaxf(fmaxf(bxmin - cx, cx - bxmax), 0.f);  // keep simple exact form
    float dlb = (ex * ex + ey * ey + ez * ez) * 0.9999f;
    bool act = dlb < cmaxv;

    if (__ballot(act)) {           // wave-uniform: any lane needs a burst?
      if (act) {
        float mv = -1.0f; int mi = 0;
#pragma unroll
        for (int k = 0; k < 8; ++k) {
          float dx = px[k] - cx, dy = py[k] - cy, dz = pz[k] - cz;
          float d = __fadd_rn(__fadd_rn(__fmul_rn(dx, dx), __fmul_rn(dy, dy)), __fmul_rn(dz, dz));
          float dm = fminf(dmin[k], d);
          dmin[k] = dm;
          if (dm > mv) { mv = dm; mi = oid[k]; }   // strict > : first max = min oid
        }
        cmaxv = mv; cmaxi = mi;
      }
      // ---- wave reduction (recomputed only when something changed) ----
      uint32_t vb = __float_as_uint(cmaxv);
      uint32_t rm = vb;
      DPP_ROR_U32_MAX(rm)   // every lane: max of its 16-lane row
      uint32_t m0 = (uint32_t)__builtin_amdgcn_readlane((int)rm, 0);
      uint32_t m1 = (uint32_t)__builtin_amdgcn_readlane((int)rm, 16);
      uint32_t m2 = (uint32_t)__builtin_amdgcn_readlane((int)rm, 32);
      uint32_t m3 = (uint32_t)__builtin_amdgcn_readlane((int)rm, 48);
      uint32_t wm = m0 > m1 ? m0 : m1;
      uint32_t wmb = m2 > m3 ? m2 : m3;
      wm = wm > wmb ? wm : wmb;
      // index stage: ballot fast path (unique max), exact DPP-min fallback
      unsigned long long em = __ballot(vb == wm);
      uint32_t wi;
      if (__popcll(em) == 1) {
        wi = (uint32_t)__builtin_amdgcn_readlane(cmaxi, __ffsll(em) - 1);
      } else {
        uint32_t ik = (vb == wm) ? (uint32_t)cmaxi : 0xFFFFFFFFu;
        DPP_ROR_U32_MIN(ik)
        uint32_t i0 = (uint32_t)__builtin_amdgcn_readlane((int)ik, 0);
        uint32_t i1 = (uint32_t)__builtin_amdgcn_readlane((int)ik, 16);
        uint32_t i2 = (uint32_t)__builtin_amdgcn_readlane((int)ik, 32);
        uint32_t i3 = (uint32_t)__builtin_amdgcn_readlane((int)ik, 48);
        wi = i0 < i1 ? i0 : i1;
        uint32_t wib = i2 < i3 ? i2 : i3;
        wi = wi < wib ? wi : wib;
      }
      wwm = wm; wwi = wi;
    }

    const int buf = t & 1;
    if (lane == 0) { rec[buf][wv].x = wwm; rec[buf][wv].y = wwi; }
    __syncthreads();

    // ---- block stage: 16 wave-winners, value then index ----
    uint2 r = rec[buf][lane & 15];
    uint32_t bm = r.x;
    DPP_ROR_U32_MAX(bm)                        // block max (rows replicate)
    uint32_t ci = (r.x == bm) ? r.y : 0xFFFFFFFFu;
    DPP_ROR_U32_MIN(ci)                        // min idx among matching waves
    int sidx = __builtin_amdgcn_readfirstlane((int)ci);

    cx = XL[3 * sidx + 0];                     // uniform LDS broadcast reads
    cy = XL[3 * sidx + 1];
    cz = XL[3 * sidx + 2];

    if (tid == 0) {
      float* o = new_xyz + ((size_t)b * NPT + t) * 3;
      o[0] = cx; o[1] = cy; o[2] = cz;
    }
  }
}

// ---------------- ball query: one wave per (b,s) ----------------
__global__ __launch_bounds__(256) void ballquery_kernel(const float* __restrict__ xyz,
                                                        const float* __restrict__ new_xyz,
                                                        int* __restrict__ idx_out) {
  const int w = blockIdx.x * 4 + (threadIdx.x >> 6);   // (b*2048 + s)
  const int lane = threadIdx.x & 63;
  const int b = w >> 11;
  const float* X = xyz + (size_t)b * NPTS * 3;
  const float cx = new_xyz[w * 3 + 0];
  const float cy = new_xyz[w * 3 + 1];
  const float cz = new_xyz[w * 3 + 2];
  int* out = idx_out + (size_t)w * NS;

  int found = 0;
  int first = -1;
  for (int base = 0; base < NPTS; base += 64) {
    const int p = base + lane;
    float x = X[p * 3 + 0], y = X[p * 3 + 1], z = X[p * 3 + 2];
    float dx = x - cx, dy = y - cy, dz = z - cz;
    float d2 = __fadd_rn(__fadd_rn(__fmul_rn(dx, dx), __fmul_rn(dy, dy)), __fmul_rn(dz, dz));
    unsigned long long mask = __ballot(d2 < R2);
    if (mask != 0ull && first < 0) first = base + __ffsll((unsigned long long)mask) - 1;
    if (found < NS) {
      if ((mask >> lane) & 1ull) {
        int rank = found + __popcll(mask & ((1ull << lane) - 1ull));
        if (rank < NS) out[rank] = p;
      }
    }
    found += __popcll(mask);
    if (found >= NS) break;
  }
  if (found < NS) {
    int pad = (first < 0) ? 0 : first;
    if (lane >= found && lane < NS) out[lane] = pad;
  }
}

// ---------------- group + MLP(67->128->256) + maxpool: one block per (b,s) ----------------
__global__ __launch_bounds__(256) void group_mlp_kernel(const float* __restrict__ xyz,
                                                        const float* __restrict__ feat,
                                                        const float* __restrict__ new_xyz,
                                                        const int* __restrict__ idx,
                                                        const float* __restrict__ w1t,
                                                        const float* __restrict__ b1,
                                                        const float* __restrict__ w2t,
                                                        const float* __restrict__ b2,
                                                        float* __restrict__ pooled) {
  const int blk = blockIdx.x;       // b*2048 + s
  const int b = blk >> 11, s = blk & 2047;
  const int tid = threadIdx.x;

  __shared__ __align__(16) float G[67 * 32];    // (C+3) x ns
  __shared__ __align__(16) float H1[128 * 32];  // 128 x ns
  __shared__ int   lidx[NS];
  __shared__ float ctr[3];

  if (tid < NS) lidx[tid] = idx[(size_t)blk * NS + tid];
  if (tid < 3)  ctr[tid] = new_xyz[blk * 3 + tid];
  __syncthreads();

  const float* F = feat + (size_t)b * CIN * NPTS;
  const float* X = xyz + (size_t)b * NPTS * 3;

  for (int e = tid; e < 67 * 32; e += 256) {
    int c = e >> 5, j = e & 31;
    int p = lidx[j];
    float v;
    if (c < 3) v = X[p * 3 + c] - ctr[c];
    else       v = F[(size_t)(c - 3) * NPTS + p];
    G[e] = v;
  }
  __syncthreads();

  // H1 = relu(W1 @ G + b1): 128x32, each thread 4o x 4j
  {
    const int oi = tid >> 3, ji = tid & 7;
    const int o0 = oi * 4, j0 = ji * 4;
    float acc[4][4];
#pragma unroll
    for (int i = 0; i < 4; ++i)
#pragma unroll
      for (int jj = 0; jj < 4; ++jj) acc[i][jj] = 0.f;
#pragma unroll 4
    for (int c = 0; c < 67; ++c) {
      float4 g  = *(const float4*)&G[c * 32 + j0];
      float4 wf = *(const float4*)&w1t[c * 128 + o0];
      float ga[4] = {g.x, g.y, g.z, g.w};
      float wa[4] = {wf.x, wf.y, wf.z, wf.w};
#pragma unroll
      for (int i = 0; i < 4; ++i)
#pragma unroll
        for (int jj = 0; jj < 4; ++jj)
          acc[i][jj] = fmaf(wa[i], ga[jj], acc[i][jj]);
    }
    float4 bb = *(const float4*)&b1[o0];
    float ba[4] = {bb.x, bb.y, bb.z, bb.w};
#pragma unroll
    for (int i = 0; i < 4; ++i) {
      float4 h;
      h.x = fmaxf(acc[i][0] + ba[i], 0.f);
      h.y = fmaxf(acc[i][1] + ba[i], 0.f);
      h.z = fmaxf(acc[i][2] + ba[i], 0.f);
      h.w = fmaxf(acc[i][3] + ba[i], 0.f);
      *(float4*)&H1[(o0 + i) * 32 + j0] = h;
    }
  }
  __syncthreads();

  // H2 = relu(W2 @ H1 + b2): 256x32, each thread 8o x 4j, then maxpool over j
  {
    const int oi = tid >> 3, ji = tid & 7;
    const int o0 = oi * 8, j0 = ji * 4;
    float acc[8][4];
#pragma unroll
    for (int i = 0; i < 8; ++i)
#pragma unroll
      for (int jj = 0; jj < 4; ++jj) acc[i][jj] = 0.f;
#pragma unroll 2
    for (int c = 0; c < 128; ++c) {
      float4 h  = *(const float4*)&H1[c * 32 + j0];
      float4 wa4 = *(const float4*)&w2t[c * 256 + o0];
      float4 wb4 = *(const float4*)&w2t[c * 256 + o0 + 4];
      float ha[4] = {h.x, h.y, h.z, h.w};
      float wa[8] = {wa4.x, wa4.y, wa4.z, wa4.w, wb4.x, wb4.y, wb4.z, wb4.w};
#pragma unroll
      for (int i = 0; i < 8; ++i)
#pragma unroll
        for (int jj = 0; jj < 4; ++jj)
          acc[i][jj] = fmaf(wa[i], ha[jj], acc[i][jj]);
    }
    float4 b2a = *(const float4*)&b2[o0];
    float4 b2b = *(const float4*)&b2[o0 + 4];
    float bb[8] = {b2a.x, b2a.y, b2a.z, b2a.w, b2b.x, b2b.y, b2b.z, b2b.w};
    float m[8];
#pragma unroll
    for (int i = 0; i < 8; ++i) {
      float v0 = fmaxf(acc[i][0] + bb[i], 0.f);
      float v1 = fmaxf(acc[i][1] + bb[i], 0.f);
      float v2 = fmaxf(acc[i][2] + bb[i], 0.f);
      float v3 = fmaxf(acc[i][3] + bb[i], 0.f);
      m[i] = fmaxf(fmaxf(v0, v1), fmaxf(v2, v3));
    }
#pragma unroll
    for (int off = 1; off < 8; off <<= 1)
#pragma unroll
      for (int i = 0; i < 8; ++i) m[i] = fmaxf(m[i], __shfl_xor(m[i], off));
    if (ji == 0) {
#pragma unroll
      for (int i = 0; i < 8; ++i)
        pooled[((size_t)b * 256 + o0 + i) * (size_t)NPT + s] = m[i];
    }
  }
}

extern "C" void kernel_launch(void* const* d_in, const int* in_sizes, int n_in,
                              void* d_out, int out_size, void* d_ws, size_t ws_size,
                              hipStream_t stream) {
  (void)in_sizes; (void)n_in; (void)out_size; (void)ws_size;
  const float* xyz  = (const float*)d_in[0];   // (4,8192,3)
  const float* feat = (const float*)d_in[1];   // (4,64,8192)
  const float* w1   = (const float*)d_in[2];   // (128,67)
  const float* b1   = (const float*)d_in[3];   // (128)
  const float* w2   = (const float*)d_in[4];   // (256,128)
  const float* b2   = (const float*)d_in[5];   // (256)

  float* out     = (float*)d_out;
  float* new_xyz = out;                        // (4,2048,3)
  float* pooled  = out + (size_t)BATCH * NPT * 3;  // (4,256,2048)

  char* ws = (char*)d_ws;
  float*  w1t    = (float*)ws;                         // 34304 B
  float*  w2t    = (float*)(ws + 34304);               // 131072 B
  int*    idx    = (int*)(ws + 34304 + 131072);        // 1048576 B
  float4* sorted = (float4*)(ws + 34304 + 131072 + 1048576);  // 524288 B (16B-aligned)

  prep_kernel<<<128, 256, 0, stream>>>(w1, w2, w1t, w2t);
  sort_kernel<<<BATCH, 1024, 0, stream>>>(xyz, sorted);
  fps_kernel<<<BATCH, 1024, 0, stream>>>(xyz, sorted, new_xyz);
  ballquery_kernel<<<(BATCH * NPT) / 4, 256, 0, stream>>>(xyz, new_xyz, idx);
  group_mlp_kernel<<<BATCH * NPT, 256, 0, stream>>>(xyz, feat, new_xyz, idx,
                                                    w1t, b1, w2t, b2, pooled);
}